// Round 1
// 78.812 us; speedup vs baseline: 1.0337x; 1.0337x over previous
//
#include <hip/hip_runtime.h>
#include <hip/hip_fp16.h>

#define TPB 256
#define MAXGRID 2048

// Padded image: 68x68 texels, texel = half2(c0, c1). Row/col p maps to
// unpadded p-2, with 2-wide reflected border baked in at staging time.
#define PW 68

__device__ __forceinline__ void cubic_w(float t, float w[4]) {
    // A = -0.75 ; s = 1-t
    float s = 1.0f - t;
    float t2 = t * t;
    float s2 = s * s;
    w[0] = -0.75f * t * s2;                       // A*t*s^2
    w[1] = 1.25f * (t2 * t) - 2.25f * t2 + 1.0f;  // (A+2)t^3-(A+3)t^2+1
    w[2] = 1.25f * (s2 * s) - 2.25f * s2 + 1.0f;
    w[3] = -0.75f * s * t2;
}

__global__ __launch_bounds__(TPB, 8) void deformation_field_kernel(
        const float4* __restrict__ coord4,   // (y0,x0,y1,x1) = two coords per float4
        const float4* __restrict__ depl4,    // 2*64*64 floats = 2048 float4
        const float4* __restrict__ mask4,
        float4* __restrict__ out4,           // (a0,a1) fp32 for two coords per float4
        int n_pairs)
{
    __shared__ __half2 img[PW * PW];  // 18,496 B -> 8 blocks/CU

    // ---- Phase 1: core 64x64 -> padded [2..65][2..65], masked, fp16-packed ----
    for (int i = threadIdx.x; i < 1024; i += TPB) {
        float4 d0 = depl4[i];          // channel 0, pixels 4i..4i+3
        float4 m0 = mask4[i];
        float4 d1 = depl4[1024 + i];   // channel 1
        float4 m1 = mask4[1024 + i];
        int o = i * 4;
        int r = o >> 6;
        int c = o & 63;                // 4-aligned, never crosses a row
        int pb = (r + 2) * PW + (c + 2);
        img[pb + 0] = __floats2half2_rn(d0.x * m0.x, d1.x * m1.x);
        img[pb + 1] = __floats2half2_rn(d0.y * m0.y, d1.y * m1.y);
        img[pb + 2] = __floats2half2_rn(d0.z * m0.z, d1.z * m1.z);
        img[pb + 3] = __floats2half2_rn(d0.w * m0.w, d1.w * m1.w);
    }
    __syncthreads();

    // ---- Phase 2a: reflected border columns for core rows ----
    // padded col 0 <- col 4, 1 <- 3, 66 <- 64, 67 <- 63  (reflect about edges)
    {
        int t = threadIdx.x;           // exactly 256 threads: 64 rows x 4 cols
        int r = 2 + (t & 63);
        int j = t >> 6;                // 0..3
        int sel = j & 1, half = j >> 1;
        int dc = half ? (66 + sel) : sel;          // 0,1,66,67
        int sc = half ? (64 - sel) : (4 - sel);    // 4,3,64,63
        img[r * PW + dc] = img[r * PW + sc];
    }
    __syncthreads();

    // ---- Phase 2b: reflected border rows (full width, incl. corners) ----
    // row 0 <- 4, 1 <- 3, 66 <- 64, 67 <- 63
    if (threadIdx.x < PW) {
        int c = threadIdx.x;
        img[0 * PW + c]  = img[4 * PW + c];
        img[1 * PW + c]  = img[3 * PW + c];
        img[66 * PW + c] = img[64 * PW + c];
        img[67 * PW + c] = img[63 * PW + c];
    }
    __syncthreads();

    // ---- Main: grid-stride over coord pairs with next-coord prefetch ----
    const int stride = gridDim.x * TPB;
    int p = blockIdx.x * TPB + threadIdx.x;
    if (p >= n_pairs) return;          // after all barriers: safe

    float4 c = coord4[p];
    for (;;) {
        int pn = p + stride;
        bool has = (pn < n_pairs);
        float4 cn;
        if (has) cn = coord4[pn];      // issue early; hides under compute

        float res[4];
        #pragma unroll
        for (int q = 0; q < 2; ++q) {
            float cyv = q ? c.z : c.x;
            float cxv = q ? c.w : c.y;
            // crop = 1/64; ix = (cx - crop + 1) * 31.5
            float ix = (cxv + 0.984375f) * 31.5f;
            float iy = (cyv + 0.984375f) * 31.5f;
            float fx = floorf(ix);
            float fy = floorf(iy);
            float tx = ix - fx;
            float ty = iy - fy;
            int jx = (int)fx;          // [-1, 62]
            int jy = (int)fy;

            float wx[4], wy[4];
            cubic_w(tx, wx);
            cubic_w(ty, wy);

            // first tap col = jx-1 -> padded jx+1; rows likewise
            int base = (jy + 1) * PW + (jx + 1);

            float a0 = 0.0f, a1 = 0.0f;
            #pragma unroll
            for (int i = 0; i < 4; ++i) {
                int rb = base + i * PW;
                __half2 t0 = img[rb + 0];
                __half2 t1 = img[rb + 1];
                __half2 t2 = img[rb + 2];
                __half2 t3 = img[rb + 3];
                float r0 = wx[0] * __low2float(t0);
                float r1 = wx[0] * __high2float(t0);
                r0 = fmaf(wx[1], __low2float(t1), r0);
                r1 = fmaf(wx[1], __high2float(t1), r1);
                r0 = fmaf(wx[2], __low2float(t2), r0);
                r1 = fmaf(wx[2], __high2float(t2), r1);
                r0 = fmaf(wx[3], __low2float(t3), r0);
                r1 = fmaf(wx[3], __high2float(t3), r1);
                a0 = fmaf(wy[i], r0, a0);
                a1 = fmaf(wy[i], r1, a1);
            }
            res[2 * q + 0] = a0;
            res[2 * q + 1] = a1;
        }
        out4[p] = make_float4(res[0], res[1], res[2], res[3]);

        if (!has) break;
        p = pn;
        c = cn;
    }
}

extern "C" void kernel_launch(void* const* d_in, const int* in_sizes, int n_in,
                              void* d_out, int out_size, void* d_ws, size_t ws_size,
                              hipStream_t stream) {
    const float4* coord4 = (const float4*)d_in[0];  // (B,2) f32
    const float4* depl4  = (const float4*)d_in[1];  // (2,64,64) f32
    const float4* mask4  = (const float4*)d_in[2];  // (2,64,64) f32
    float4* out4 = (float4*)d_out;                  // (B,2) f32 -> B/2 float4

    int n_pairs = in_sizes[0] / 4;  // B/2
    // 2 pairs per thread at full size: 2048 blocks -> 8 blocks/CU (LDS 18.5 KB)
    int grid = (n_pairs + 2 * TPB - 1) / (2 * TPB);
    if (grid > MAXGRID) grid = MAXGRID;
    if (grid < 1) grid = 1;

    deformation_field_kernel<<<grid, TPB, 0, stream>>>(coord4, depl4, mask4, out4, n_pairs);
}